// Round 2
// baseline (392.258 us; speedup 1.0000x reference)
//
#include <hip/hip_runtime.h>
#include <math.h>

// MultiHeadBigBirdAttention: B=2, S=2048, E=1024, H=8, DH=128
// Pipeline (all bf16 MFMA 16x16x32):
//   1. wtrans: Wq/Wk/Wv/Wo fp32 [K][N] -> bf16 W^T [N][K] (contiguous in ws)
//   2. conv_k: q,k,v fp32 -> bf16
//   3. gemm_k<0> (grid.z=3): {q,k,v}b @ W^T + b -> Qh/Kh [B,H,S,DH], Vt [B,H,DH,S]
//   4. flash_k: online-softmax attention -> ctx bf16 [B*S, E]
//   5. gemm_k<1>: ctx @ Wo^T + bo -> d_out fp32
//
// MFMA layouts (verified learn_hip m89/m91/m120):
//   C/D: col = lane&15, row = (lane>>4)*4 + reg
//   A:   m   = lane&15, k   = (lane>>4)*8 + j
//   B:   n   = lane&15, k   = (lane>>4)*8 + j

typedef __bf16 bf16_t;
typedef __bf16 bf16x8 __attribute__((ext_vector_type(8)));
typedef float f32x4 __attribute__((ext_vector_type(4)));

#define MFMA16(a, b, c) __builtin_amdgcn_mfma_f32_16x16x32_bf16(a, b, c, 0, 0, 0)

// async global->LDS, 16B per lane; LDS dest = base + lane*16 (wave-uniform base)
__device__ __forceinline__ void gld16(const bf16_t* g, bf16_t* l) {
  __builtin_amdgcn_global_load_lds(
      (const __attribute__((address_space(1))) void*)g,
      (__attribute__((address_space(3))) void*)l, 16, 0, 0);
}

// ---------------------------------------------------------------------------
// Weight transpose + fp32->bf16: W [1024][1024] -> W^T bf16, 4 matrices
// ---------------------------------------------------------------------------
__global__ __launch_bounds__(256) void wtrans(const float* W0, const float* W1,
                                              const float* W2, const float* W3,
                                              bf16_t* out) {
  const float* W = (blockIdx.z == 0) ? W0 : (blockIdx.z == 1) ? W1
                                          : (blockIdx.z == 2) ? W2 : W3;
  bf16_t* o = out + (size_t)blockIdx.z * 1024 * 1024;
  __shared__ float t[32][33];
  int n0 = blockIdx.x * 32, k0 = blockIdx.y * 32;
  int tx = threadIdx.x, ty = threadIdx.y;
#pragma unroll
  for (int i = 0; i < 4; i++)
    t[ty + 8 * i][tx] = W[(size_t)(k0 + ty + 8 * i) * 1024 + n0 + tx];
  __syncthreads();
#pragma unroll
  for (int i = 0; i < 4; i++)
    o[(size_t)(n0 + ty + 8 * i) * 1024 + k0 + tx] = (bf16_t)t[tx][ty + 8 * i];
}

// ---------------------------------------------------------------------------
// fp32 -> bf16 convert for q,k,v (4M elems each), 8 elems/thread
// ---------------------------------------------------------------------------
__global__ __launch_bounds__(256) void conv_k(const float* q, const float* k,
                                              const float* v, bf16_t* qb,
                                              bf16_t* kb, bf16_t* vb) {
  const float* x = (blockIdx.y == 0) ? q : (blockIdx.y == 1) ? k : v;
  bf16_t* y = (blockIdx.y == 0) ? qb : (blockIdx.y == 1) ? kb : vb;
  size_t i = ((size_t)blockIdx.x * 256 + threadIdx.x) * 8;
  float4 a = *(const float4*)(x + i);
  float4 b = *(const float4*)(x + i + 4);
  bf16x8 o = {(bf16_t)a.x, (bf16_t)a.y, (bf16_t)a.z, (bf16_t)a.w,
              (bf16_t)b.x, (bf16_t)b.y, (bf16_t)b.z, (bf16_t)b.w};
  *(bf16x8*)(y + i) = o;
}

// ---------------------------------------------------------------------------
// GEMM 128x128 tile, BK=64, global_load_lds staging (m97 structure).
// MODE 0: QKV (blockIdx.z selects A/Bt/bias; out -> head layouts, bf16)
// MODE 1: out-projection (fp32 plain [M][N], N=1024)
// ---------------------------------------------------------------------------
template <int MODE>
__global__ __launch_bounds__(256) void gemm_k(
    const bf16_t* qb, const bf16_t* kb, const bf16_t* vb, const bf16_t* Wt,
    const float* b0, const float* b1, const float* b2, bf16_t* Qh, bf16_t* Kh,
    bf16_t* Vt, float* Of32) {
  __shared__ bf16_t As[128 * 64];
  __shared__ bf16_t Bs[128 * 64];
  const int tid = threadIdx.x, w = tid >> 6, lane = tid & 63;
  const int bm = blockIdx.y, bn = blockIdx.x;
  const int wr = w >> 1, wc = w & 1, q4 = lane >> 4, lo = lane & 15;
  const int z = (MODE == 0) ? blockIdx.z : 3;
  const bf16_t* A = (MODE == 1) ? qb : (z == 0) ? qb : (z == 1) ? kb : vb;
  const bf16_t* Bt = Wt + (size_t)z * 1024 * 1024;
  const float* bias = (MODE == 1) ? b0 : (z == 0) ? b0 : (z == 1) ? b1 : b2;

  f32x4 acc[4][4];
#pragma unroll
  for (int m = 0; m < 4; m++)
#pragma unroll
    for (int n = 0; n < 4; n++) acc[m][n] = (f32x4){0.f, 0.f, 0.f, 0.f};

  const int lr = lane >> 3, lc = lane & 7;  // staging: 8 rows x 8 chunks of 16B

  for (int k0 = 0; k0 < 1024; k0 += 64) {
#pragma unroll
    for (int c = 0; c < 4; c++) {
      int row = w * 32 + c * 8;
      gld16(A + (size_t)(bm * 128 + row + lr) * 1024 + k0 + lc * 8,
            &As[row * 64]);
      gld16(Bt + (size_t)(bn * 128 + row + lr) * 1024 + k0 + lc * 8,
            &Bs[row * 64]);
    }
    __syncthreads();
#pragma unroll
    for (int kc = 0; kc < 2; kc++) {
      bf16x8 af[4], bfr[4];
#pragma unroll
      for (int m = 0; m < 4; m++)
        af[m] = *(const bf16x8*)&As[(wr * 64 + m * 16 + lo) * 64 +
                                    (kc * 4 + q4) * 8];
#pragma unroll
      for (int n = 0; n < 4; n++)
        bfr[n] = *(const bf16x8*)&Bs[(wc * 64 + n * 16 + lo) * 64 +
                                     (kc * 4 + q4) * 8];
#pragma unroll
      for (int m = 0; m < 4; m++)
#pragma unroll
        for (int n = 0; n < 4; n++)
          acc[m][n] = MFMA16(af[m], bfr[n], acc[m][n]);
    }
    __syncthreads();
  }

  // epilogue
#pragma unroll
  for (int m = 0; m < 4; m++) {
#pragma unroll
    for (int n = 0; n < 4; n++) {
      int rowg0 = bm * 128 + wr * 64 + m * 16 + q4 * 4;
      int colg = bn * 128 + wc * 64 + n * 16 + lo;
      float bv = bias[colg];
#pragma unroll
      for (int rg = 0; rg < 4; rg++) {
        float val = acc[m][n][rg] + bv;
        int row = rowg0 + rg;
        if (MODE == 1) {
          Of32[(size_t)row * 1024 + colg] = val;
        } else {
          int b = row >> 11, s = row & 2047;  // S=2048
          int h = colg >> 7, d = colg & 127;  // DH=128
          if (z == 0)
            Qh[(((size_t)(b * 8 + h)) * 2048 + s) * 128 + d] = (bf16_t)val;
          else if (z == 1)
            Kh[(((size_t)(b * 8 + h)) * 2048 + s) * 128 + d] = (bf16_t)val;
          else
            Vt[(((size_t)(b * 8 + h)) * 128 + d) * 2048 + s] = (bf16_t)val;
        }
      }
    }
  }
}

// ---------------------------------------------------------------------------
// Flash attention: grid (32, B*H), block 256 (4 waves x 16 q-rows).
// LDS 40KB union: Ks @0 (8192 e), Vs @8192 (8192 e), Ps @16384 (4096 e).
// Q staged through Ks region pre-loop. K/V staged via global_load_lds.
// ---------------------------------------------------------------------------
__global__ __launch_bounds__(256, 4) void flash_k(const bf16_t* Qh,
                                                  const bf16_t* Kh,
                                                  const bf16_t* Vt, bf16_t* ctx,
                                                  const int* causal_p) {
  __shared__ bf16_t sm[20480];
  const int tid = threadIdx.x, w = tid >> 6, lane = tid & 63;
  const int qt = blockIdx.x, bh = blockIdx.y;
  const int q4 = lane >> 4, lo = lane & 15;
  const int causal = *causal_p;

  // ---- stage Q (plain [64][128]) into Ks region, hoist A-frags ----
  {
    int r = tid >> 2, seg = tid & 3;
    const bf16_t* src = Qh + ((size_t)bh * 2048 + qt * 64 + r) * 128 + seg * 32;
#pragma unroll
    for (int i = 0; i < 4; i++)
      *(bf16x8*)&sm[r * 128 + seg * 32 + i * 8] = *(const bf16x8*)(src + i * 8);
  }
  __syncthreads();
  bf16x8 aq[4];
  {
    int rr = w * 16 + lo;
#pragma unroll
    for (int ks = 0; ks < 4; ks++)
      aq[ks] = *(const bf16x8*)&sm[rr * 128 + (ks * 4 + q4) * 8];
  }

  float m_run[4], l_run[4];
  f32x4 acc[8];
#pragma unroll
  for (int i = 0; i < 4; i++) { m_run[i] = -INFINITY; l_run[i] = 0.f; }
#pragma unroll
  for (int i = 0; i < 8; i++) acc[i] = (f32x4){0.f, 0.f, 0.f, 0.f};

  const float sc2 = 0.08838834764831845f * 1.44269504088896f;  // /sqrt(DH)*log2e
  const int ktmax = causal ? qt : 31;

  for (int kt = 0; kt <= ktmax; ++kt) {
    __syncthreads();  // smem free (Q hoisted / prev iter done)
    // ---- stage K [64 rows x 128 dh] and V^T [128 d x 64 keys] ----
#pragma unroll
    for (int c = 0; c < 4; c++) {
      int j = w * 4 + c;
      gld16(Kh + ((size_t)bh * 2048 + kt * 64 + j * 4 + (lane >> 4)) * 128 +
                (lane & 15) * 8,
            &sm[j * 4 * 128]);
      gld16(Vt + ((size_t)bh * 128 + j * 8 + (lane >> 3)) * 2048 + kt * 64 +
                (lane & 7) * 8,
            &sm[8192 + j * 8 * 64]);
    }
    __syncthreads();

    // ---- scores: wave computes 16 q-rows x 64 keys ----
    f32x4 sa[4];
#pragma unroll
    for (int nt = 0; nt < 4; nt++) {
      sa[nt] = (f32x4){0.f, 0.f, 0.f, 0.f};
      int key = nt * 16 + lo;
#pragma unroll
      for (int ks = 0; ks < 4; ks++) {
        bf16x8 bk = *(const bf16x8*)&sm[key * 128 + (ks * 4 + q4) * 8];
        sa[nt] = MFMA16(aq[ks], bk, sa[nt]);
      }
    }

    // ---- online softmax (log2 domain); mask only diagonal tile ----
    const bool diag = causal && (kt == qt);
    float p[4][4];
#pragma unroll
    for (int rg = 0; rg < 4; rg++) {
      float mx = -INFINITY;
#pragma unroll
      for (int nt = 0; nt < 4; nt++) {
        float s = sa[nt][rg] * sc2;
        if (diag) {
          int rowq = w * 16 + q4 * 4 + rg;
          int colk = nt * 16 + lo;
          if (colk > rowq) s = -INFINITY;
        }
        p[nt][rg] = s;
        mx = fmaxf(mx, s);
      }
#pragma unroll
      for (int off = 1; off < 16; off <<= 1) mx = fmaxf(mx, __shfl_xor(mx, off));
      float mn = fmaxf(m_run[rg], mx);
      float alpha = exp2f(m_run[rg] - mn);
      float sum = 0.f;
#pragma unroll
      for (int nt = 0; nt < 4; nt++) {
        float e = exp2f(p[nt][rg] - mn);
        p[nt][rg] = e;
        sum += e;
      }
#pragma unroll
      for (int off = 1; off < 16; off <<= 1) sum += __shfl_xor(sum, off);
      l_run[rg] = l_run[rg] * alpha + sum;
      m_run[rg] = mn;
#pragma unroll
      for (int nt2 = 0; nt2 < 8; nt2++) acc[nt2][rg] *= alpha;
    }

    // ---- P: C/D layout -> A layout via per-wave LDS (swizzled chunks) ----
#pragma unroll
    for (int nt = 0; nt < 4; nt++) {
#pragma unroll
      for (int rg = 0; rg < 4; rg++) {
        int rr = q4 * 4 + rg;
        int kk = nt * 16 + lo;
        sm[16384 + w * 1024 + rr * 64 + (((kk >> 3) ^ (rr & 7)) * 8) +
           (kk & 7)] = (bf16_t)p[nt][rg];
      }
    }

    // ---- PV: acc += P @ V (16 rows x 128 dh, K=64) ----
#pragma unroll
    for (int ks = 0; ks < 2; ks++) {
      int c = ks * 4 + q4;
      bf16x8 ap =
          *(const bf16x8*)&sm[16384 + w * 1024 + lo * 64 + ((c ^ (lo & 7)) * 8)];
#pragma unroll
      for (int nt2 = 0; nt2 < 8; nt2++) {
        int d = nt2 * 16 + lo;
        bf16x8 bv = *(const bf16x8*)&sm[8192 + d * 64 + (ks * 4 + q4) * 8];
        acc[nt2] = MFMA16(ap, bv, acc[nt2]);
      }
    }
  }

  // ---- epilogue ----
  int b = bh >> 3, h = bh & 7;
#pragma unroll
  for (int rg = 0; rg < 4; rg++) {
    float inv = 1.f / l_run[rg];
    int t = b * 2048 + qt * 64 + w * 16 + q4 * 4 + rg;
#pragma unroll
    for (int nt2 = 0; nt2 < 8; nt2++)
      ctx[(size_t)t * 1024 + h * 128 + nt2 * 16 + lo] =
          (bf16_t)(acc[nt2][rg] * inv);
  }
}

// ---------------------------------------------------------------------------
extern "C" void kernel_launch(void* const* d_in, const int* in_sizes, int n_in,
                              void* d_out, int out_size, void* d_ws,
                              size_t ws_size, hipStream_t stream) {
  const float* q = (const float*)d_in[0];
  const float* k = (const float*)d_in[1];
  const float* v = (const float*)d_in[2];
  const float* Wq = (const float*)d_in[3];
  const float* bq = (const float*)d_in[4];
  const float* Wk = (const float*)d_in[5];
  const float* bk = (const float*)d_in[6];
  const float* Wv = (const float*)d_in[7];
  const float* bv = (const float*)d_in[8];
  const float* Wo = (const float*)d_in[9];
  const float* bo = (const float*)d_in[10];
  const int* isc = (const int*)d_in[11];

  char* ws = (char*)d_ws;
  bf16_t* Wt = (bf16_t*)ws;                     // 8MB: Wq^T,Wk^T,Wv^T,Wo^T bf16
  bf16_t* qb = (bf16_t*)(ws + (8ull << 20));    // 8MB bf16 [4096][1024]
  bf16_t* kb = (bf16_t*)(ws + (16ull << 20));   // 8MB
  bf16_t* vb = (bf16_t*)(ws + (24ull << 20));   // 8MB
  bf16_t* Qh = (bf16_t*)(ws + (32ull << 20));   // 8MB [B,H,S,DH]
  bf16_t* Kh = (bf16_t*)(ws + (40ull << 20));   // 8MB [B,H,S,DH]
  bf16_t* Vt = (bf16_t*)(ws + (48ull << 20));   // 8MB [B,H,DH,S]
  bf16_t* ctx = (bf16_t*)(ws + (8ull << 20));   // reuse qb (dead after QKV gemm)

  wtrans<<<dim3(32, 32, 4), dim3(32, 8), 0, stream>>>(Wq, Wk, Wv, Wo, Wt);
  conv_k<<<dim3(2048, 3), 256, 0, stream>>>(q, k, v, qb, kb, vb);

  gemm_k<0><<<dim3(8, 32, 3), 256, 0, stream>>>(qb, kb, vb, Wt, bq, bk, bv, Qh,
                                                Kh, Vt, nullptr);

  flash_k<<<dim3(32, 16), 256, 0, stream>>>(Qh, Kh, Vt, ctx, isc);

  gemm_k<1><<<dim3(8, 32), 256, 0, stream>>>(ctx, nullptr, nullptr, Wt, bo,
                                             nullptr, nullptr, nullptr, nullptr,
                                             nullptr, (float*)d_out);
}

// Round 3
// 299.459 us; speedup vs baseline: 1.3099x; 1.3099x over previous
//
#include <hip/hip_runtime.h>
#include <math.h>

// MultiHeadBigBirdAttention: B=2, S=2048, E=1024, H=8, DH=128
// Pipeline (bf16 MFMA 16x16x32):
//   1. wtrans: W* fp32 [K][N] -> bf16 W^T [N][K]
//   2. conv_k: q,k,v fp32 -> bf16
//   3. gemm_k<0> (grid.z=3): projections -> Qh/Kh [B,H,S,DH], Vt [B,H,DH,S]
//   4. flash_k: barrier-free per-wave flash attention -> ctx bf16 [B*S, E]
//   5. gemm_k<1>: ctx @ Wo^T + bo -> d_out fp32
//
// MFMA layouts (verified learn_hip m89/m91/m120):
//   C/D: col = lane&15, row = (lane>>4)*4 + reg
//   A:   m   = lane&15, k   = (lane>>4)*8 + j
//   B:   n   = lane&15, k   = (lane>>4)*8 + j
// All LDS tiles XOR-chunk-swizzled; gld16 staging uses INVERSE swizzle on the
// per-lane global source address (LDS dest of global_load_lds is fixed).

typedef __bf16 bf16_t;
typedef __bf16 bf16x8 __attribute__((ext_vector_type(8)));
typedef float f32x4 __attribute__((ext_vector_type(4)));

#define MFMA16(a, b, c) __builtin_amdgcn_mfma_f32_16x16x32_bf16(a, b, c, 0, 0, 0)

__device__ __forceinline__ void gld16(const bf16_t* g, bf16_t* l) {
  __builtin_amdgcn_global_load_lds(
      (const __attribute__((address_space(1))) void*)g,
      (__attribute__((address_space(3))) void*)l, 16, 0, 0);
}

// ---------------------------------------------------------------------------
__global__ __launch_bounds__(256) void wtrans(const float* W0, const float* W1,
                                              const float* W2, const float* W3,
                                              bf16_t* out) {
  const float* W = (blockIdx.z == 0) ? W0 : (blockIdx.z == 1) ? W1
                                          : (blockIdx.z == 2) ? W2 : W3;
  bf16_t* o = out + (size_t)blockIdx.z * 1024 * 1024;
  __shared__ float t[32][33];
  int n0 = blockIdx.x * 32, k0 = blockIdx.y * 32;
  int tx = threadIdx.x, ty = threadIdx.y;
#pragma unroll
  for (int i = 0; i < 4; i++)
    t[ty + 8 * i][tx] = W[(size_t)(k0 + ty + 8 * i) * 1024 + n0 + tx];
  __syncthreads();
#pragma unroll
  for (int i = 0; i < 4; i++)
    o[(size_t)(n0 + ty + 8 * i) * 1024 + k0 + tx] = (bf16_t)t[tx][ty + 8 * i];
}

// ---------------------------------------------------------------------------
__global__ __launch_bounds__(256) void conv_k(const float* q, const float* k,
                                              const float* v, bf16_t* qb,
                                              bf16_t* kb, bf16_t* vb) {
  const float* x = (blockIdx.y == 0) ? q : (blockIdx.y == 1) ? k : v;
  bf16_t* y = (blockIdx.y == 0) ? qb : (blockIdx.y == 1) ? kb : vb;
  size_t i = ((size_t)blockIdx.x * 256 + threadIdx.x) * 8;
  float4 a = *(const float4*)(x + i);
  float4 b = *(const float4*)(x + i + 4);
  bf16x8 o = {(bf16_t)a.x, (bf16_t)a.y, (bf16_t)a.z, (bf16_t)a.w,
              (bf16_t)b.x, (bf16_t)b.y, (bf16_t)b.z, (bf16_t)b.w};
  *(bf16x8*)(y + i) = o;
}

// ---------------------------------------------------------------------------
// GEMM 128x128 tile, BK=64, gld16 staging with inverse-swizzled sources.
// LDS [128][64], chunk (8 elems) swizzle: slot(r,c) holds global chunk c^(r&7).
// ---------------------------------------------------------------------------
template <int MODE>
__global__ __launch_bounds__(256) void gemm_k(
    const bf16_t* qb, const bf16_t* kb, const bf16_t* vb, const bf16_t* Wt,
    const float* b0, const float* b1, const float* b2, bf16_t* Qh, bf16_t* Kh,
    bf16_t* Vt, float* Of32) {
  __shared__ bf16_t As[128 * 64];
  __shared__ bf16_t Bs[128 * 64];
  const int tid = threadIdx.x, w = tid >> 6, lane = tid & 63;
  const int bm = blockIdx.y, bn = blockIdx.x;
  const int wr = w >> 1, wc = w & 1, q4 = lane >> 4, lo = lane & 15;
  const int z = (MODE == 0) ? blockIdx.z : 3;
  const bf16_t* A = (MODE == 1) ? qb : (z == 0) ? qb : (z == 1) ? kb : vb;
  const bf16_t* Bt = Wt + (size_t)z * 1024 * 1024;
  const float* bias = (MODE == 1) ? b0 : (z == 0) ? b0 : (z == 1) ? b1 : b2;

  f32x4 acc[4][4];
#pragma unroll
  for (int m = 0; m < 4; m++)
#pragma unroll
    for (int n = 0; n < 4; n++) acc[m][n] = (f32x4){0.f, 0.f, 0.f, 0.f};

  const int lr = lane >> 3, lc = lane & 7;       // 8 rows x 8 chunks per gld
  const int scol = (lc ^ lr) * 8;                // inverse swizzle source chunk

  for (int k0 = 0; k0 < 1024; k0 += 64) {
#pragma unroll
    for (int c = 0; c < 4; c++) {
      int row = w * 32 + c * 8;
      gld16(A + (size_t)(bm * 128 + row + lr) * 1024 + k0 + scol, &As[row * 64]);
      gld16(Bt + (size_t)(bn * 128 + row + lr) * 1024 + k0 + scol, &Bs[row * 64]);
    }
    __syncthreads();
#pragma unroll
    for (int kc = 0; kc < 2; kc++) {
      bf16x8 af[4], bfr[4];
#pragma unroll
      for (int m = 0; m < 4; m++) {
        int rr = wr * 64 + m * 16 + lo;
        af[m] = *(const bf16x8*)&As[rr * 64 + ((kc * 4 + q4) ^ (rr & 7)) * 8];
      }
#pragma unroll
      for (int n = 0; n < 4; n++) {
        int rr = wc * 64 + n * 16 + lo;
        bfr[n] = *(const bf16x8*)&Bs[rr * 64 + ((kc * 4 + q4) ^ (rr & 7)) * 8];
      }
#pragma unroll
      for (int m = 0; m < 4; m++)
#pragma unroll
        for (int n = 0; n < 4; n++)
          acc[m][n] = MFMA16(af[m], bfr[n], acc[m][n]);
    }
    __syncthreads();
  }

#pragma unroll
  for (int m = 0; m < 4; m++) {
#pragma unroll
    for (int n = 0; n < 4; n++) {
      int rowg0 = bm * 128 + wr * 64 + m * 16 + q4 * 4;
      int colg = bn * 128 + wc * 64 + n * 16 + lo;
      float bv = bias[colg];
#pragma unroll
      for (int rg = 0; rg < 4; rg++) {
        float val = acc[m][n][rg] + bv;
        int row = rowg0 + rg;
        if (MODE == 1) {
          Of32[(size_t)row * 1024 + colg] = val;
        } else {
          int b = row >> 11, s = row & 2047;  // S=2048
          int h = colg >> 7, d = colg & 127;  // DH=128
          if (z == 0)
            Qh[(((size_t)(b * 8 + h)) * 2048 + s) * 128 + d] = (bf16_t)val;
          else if (z == 1)
            Kh[(((size_t)(b * 8 + h)) * 2048 + s) * 128 + d] = (bf16_t)val;
          else
            Vt[(((size_t)(b * 8 + h)) * 128 + d) * 2048 + s] = (bf16_t)val;
        }
      }
    }
  }
}

// ---------------------------------------------------------------------------
// Barrier-free per-wave flash attention.
// Grid (32,16) x 256 thr. Each WAVE owns one 16-row Q-tile, loops 32-key
// K/V tiles with register prefetch; NO __syncthreads in the loop.
// Per-wave LDS (8192 elems): Ks [32 key][128 dh] (4096, chunk^(key&7)),
// Vs [128 d][32 key] (4096, chunk^((d>>1)&3)), Ps [16][40] aliases Ks head.
// Block remap: blocks c and c+256 (same CU under round-robin / XCD-swizzle)
// get complementary qt work (qt vs 127-qt) -> balanced CU load.
// ---------------------------------------------------------------------------
__global__ __launch_bounds__(256, 2) void flash_k(const bf16_t* Qh,
                                                  const bf16_t* Kh,
                                                  const bf16_t* Vt, bf16_t* ctx,
                                                  const int* causal_p) {
  __shared__ bf16_t sm[32768];
  const int tid = threadIdx.x, w = tid >> 6, lane = tid & 63;
  const int q4 = lane >> 4, lo = lane & 15;

  int c = blockIdx.x + 32 * blockIdx.y;
  int t8 = c & 255, hi = c >> 8;
  int bh = (t8 >> 5) + 8 * hi;
  int qt = (t8 & 31) * 4 + w;
  if (hi) qt = 127 - qt;

  bf16_t* Ks = sm + w * 8192;
  bf16_t* Vs = Ks + 4096;
  bf16_t* Ps = Ks;  // alias: P written after scores consume Ks, dead by next kt

  const int causal = *causal_p;
  const int ktmax = causal ? (qt >> 1) : 63;

  // Q A-fragments straight from global (lane m=lo, k=ks*32+q4*8+j)
  bf16x8 aq[4];
  {
    const bf16_t* Qrow = Qh + ((size_t)bh * 2048 + qt * 16 + lo) * 128;
#pragma unroll
    for (int ks = 0; ks < 4; ks++)
      aq[ks] = *(const bf16x8*)(Qrow + ks * 32 + q4 * 8);
  }

  const bf16_t* Kbase = Kh + (size_t)bh * 2048 * 128;
  const bf16_t* Vbase = Vt + (size_t)bh * 128 * 2048;
  const int klr = lane >> 4, klc = lane & 15;  // K: 4 rows x 16 chunks / ld
  const int vlr = lane >> 2, vlc = lane & 3;   // V: 16 rows x 4 chunks / ld

  bf16x8 kreg[8], vreg[8];
#pragma unroll
  for (int j = 0; j < 8; j++) {
    kreg[j] = *(const bf16x8*)(Kbase + (size_t)(j * 4 + klr) * 128 + klc * 8);
    vreg[j] = *(const bf16x8*)(Vbase + (size_t)(j * 16 + vlr) * 2048 + vlc * 8);
  }

  float m_run[4], l_run[4];
  f32x4 acc[8];
#pragma unroll
  for (int i = 0; i < 4; i++) { m_run[i] = -INFINITY; l_run[i] = 0.f; }
#pragma unroll
  for (int i = 0; i < 8; i++) acc[i] = (f32x4){0.f, 0.f, 0.f, 0.f};

  const float sc2 = 0.08838834764831845f * 1.44269504088896f;

  for (int kt = 0; kt <= ktmax; ++kt) {
    // ---- deposit current tile to LDS (swizzled; same-wave ordering) ----
#pragma unroll
    for (int j = 0; j < 8; j++) {
      int r = j * 4 + klr;
      *(bf16x8*)&Ks[r * 128 + (klc ^ (r & 7)) * 8] = kreg[j];
    }
#pragma unroll
    for (int j = 0; j < 8; j++) {
      int d = j * 16 + vlr;
      *(bf16x8*)&Vs[d * 32 + (vlc ^ ((d >> 1) & 3)) * 8] = vreg[j];
    }
    // ---- prefetch next tile into registers (lands during compute) ----
    if (kt < ktmax) {
      const bf16_t* kp = Kbase + (size_t)(kt + 1) * 32 * 128;
      const bf16_t* vp = Vbase + (size_t)(kt + 1) * 32;
#pragma unroll
      for (int j = 0; j < 8; j++) {
        kreg[j] = *(const bf16x8*)(kp + (size_t)(j * 4 + klr) * 128 + klc * 8);
        vreg[j] = *(const bf16x8*)(vp + (size_t)(j * 16 + vlr) * 2048 + vlc * 8);
      }
    }

    // ---- scores: 16 q-rows x 32 keys ----
    f32x4 sa[2];
#pragma unroll
    for (int nt = 0; nt < 2; nt++) {
      sa[nt] = (f32x4){0.f, 0.f, 0.f, 0.f};
      int key = nt * 16 + lo;
#pragma unroll
      for (int ks = 0; ks < 4; ks++) {
        bf16x8 bk = *(const bf16x8*)&Ks[key * 128 + ((ks * 4 + q4) ^ (key & 7)) * 8];
        sa[nt] = MFMA16(aq[ks], bk, sa[nt]);
      }
    }

    // ---- online softmax ----
    const bool diag = causal && (kt == (qt >> 1));
    const int rbase = (qt & 1) * 16;
    float p[2][4];
#pragma unroll
    for (int rg = 0; rg < 4; rg++) {
      float mx = -INFINITY;
#pragma unroll
      for (int nt = 0; nt < 2; nt++) {
        float s = sa[nt][rg] * sc2;
        if (diag && (nt * 16 + lo) > (rbase + q4 * 4 + rg)) s = -INFINITY;
        p[nt][rg] = s;
        mx = fmaxf(mx, s);
      }
#pragma unroll
      for (int off = 1; off < 16; off <<= 1) mx = fmaxf(mx, __shfl_xor(mx, off));
      float mn = fmaxf(m_run[rg], mx);
      float alpha = exp2f(m_run[rg] - mn);
      float sum = 0.f;
#pragma unroll
      for (int nt = 0; nt < 2; nt++) {
        float e = exp2f(p[nt][rg] - mn);
        p[nt][rg] = e;
        sum += e;
      }
#pragma unroll
      for (int off = 1; off < 16; off <<= 1) sum += __shfl_xor(sum, off);
      l_run[rg] = l_run[rg] * alpha + sum;
      m_run[rg] = mn;
#pragma unroll
      for (int nt2 = 0; nt2 < 8; nt2++) acc[nt2][rg] *= alpha;
    }

    // ---- P (C/D) -> A layout via per-wave LDS, row stride 40 ----
#pragma unroll
    for (int nt = 0; nt < 2; nt++)
#pragma unroll
      for (int rg = 0; rg < 4; rg++)
        Ps[(q4 * 4 + rg) * 40 + nt * 16 + lo] = (bf16_t)p[nt][rg];

    // ---- PV: acc += P[16x32] @ V[32x128] ----
    {
      bf16x8 ap = *(const bf16x8*)&Ps[lo * 40 + q4 * 8];
#pragma unroll
      for (int nt2 = 0; nt2 < 8; nt2++) {
        int d = nt2 * 16 + lo;
        bf16x8 bv = *(const bf16x8*)&Vs[d * 32 + (q4 ^ ((d >> 1) & 3)) * 8];
        acc[nt2] = MFMA16(ap, bv, acc[nt2]);
      }
    }
  }

  // ---- epilogue ----
  int b = bh >> 3, h = bh & 7;
#pragma unroll
  for (int rg = 0; rg < 4; rg++) {
    float inv = 1.f / l_run[rg];
    int trow = b * 2048 + qt * 16 + q4 * 4 + rg;
#pragma unroll
    for (int nt2 = 0; nt2 < 8; nt2++)
      ctx[(size_t)trow * 1024 + h * 128 + nt2 * 16 + lo] =
          (bf16_t)(acc[nt2][rg] * inv);
  }
}

// ---------------------------------------------------------------------------
extern "C" void kernel_launch(void* const* d_in, const int* in_sizes, int n_in,
                              void* d_out, int out_size, void* d_ws,
                              size_t ws_size, hipStream_t stream) {
  const float* q = (const float*)d_in[0];
  const float* k = (const float*)d_in[1];
  const float* v = (const float*)d_in[2];
  const float* Wq = (const float*)d_in[3];
  const float* bq = (const float*)d_in[4];
  const float* Wk = (const float*)d_in[5];
  const float* bk = (const float*)d_in[6];
  const float* Wv = (const float*)d_in[7];
  const float* bv = (const float*)d_in[8];
  const float* Wo = (const float*)d_in[9];
  const float* bo = (const float*)d_in[10];
  const int* isc = (const int*)d_in[11];

  char* ws = (char*)d_ws;
  bf16_t* Wt = (bf16_t*)ws;                     // 8MB: W^T bf16 x4
  bf16_t* qb = (bf16_t*)(ws + (8ull << 20));    // 8MB
  bf16_t* kb = (bf16_t*)(ws + (16ull << 20));   // 8MB
  bf16_t* vb = (bf16_t*)(ws + (24ull << 20));   // 8MB
  bf16_t* Qh = (bf16_t*)(ws + (32ull << 20));   // 8MB [B,H,S,DH]
  bf16_t* Kh = (bf16_t*)(ws + (40ull << 20));   // 8MB [B,H,S,DH]
  bf16_t* Vt = (bf16_t*)(ws + (48ull << 20));   // 8MB [B,H,DH,S]
  bf16_t* ctx = (bf16_t*)(ws + (8ull << 20));   // reuse qb

  wtrans<<<dim3(32, 32, 4), dim3(32, 8), 0, stream>>>(Wq, Wk, Wv, Wo, Wt);
  conv_k<<<dim3(2048, 3), 256, 0, stream>>>(q, k, v, qb, kb, vb);

  gemm_k<0><<<dim3(8, 32, 3), 256, 0, stream>>>(qb, kb, vb, Wt, bq, bk, bv, Qh,
                                                Kh, Vt, nullptr);

  flash_k<<<dim3(32, 16), 256, 0, stream>>>(Qh, Kh, Vt, ctx, isc);

  gemm_k<1><<<dim3(8, 32), 256, 0, stream>>>(ctx, nullptr, nullptr, Wt, bo,
                                             nullptr, nullptr, nullptr, nullptr,
                                             nullptr, (float*)d_out);
}